// Round 7
// baseline (300.633 us; speedup 1.0000x reference)
//
#include <hip/hip_runtime.h>
#include <stdint.h>

#define THREADS 256
#define BPB 4                     // boards per block
#define CELLS (BPB * 81)          // 324 cells per block
#define NVEC  (BPB * 729 / 4)     // 729 float4 staging tiles
#define NBLK  (65536 / BPB)       // 16384 blocks

__launch_bounds__(THREADS, 8)     // 8 waves/SIMD -> 8 blocks/CU, cap VGPR at 64
static __global__ void sudoku_main(const float* __restrict__ outs,
                                   const int*   __restrict__ targets,
                                   float*       __restrict__ partials) {
    __shared__ __align__(16) float L[BPB * 729];   // 11664 B; logits, then probs in place
    __shared__ float wave_sums[THREADS / 64];

    const int tid  = threadIdx.x;
    const int lane = tid & 63;
    const int wv   = tid >> 6;
    const long long board0 = (long long)blockIdx.x * BPB;
    const float* __restrict__ gsrc = outs + board0 * 729;
    const int*   __restrict__ tsrc = targets + board0 * 81;

    // ---- Stage: async global -> LDS DMA, width 16 (global_load_lds_dwordx4) ----
    #pragma unroll
    for (int k = 0; k < 3; ++k) {
        const int vbase = k * THREADS + wv * 64;   // wave-uniform float4 index
        const int idx   = vbase + lane;
        if (idx < NVEC) {
            __builtin_amdgcn_global_load_lds(
                (const __attribute__((address_space(1))) void*)(gsrc + (size_t)idx * 4),
                (__attribute__((address_space(3))) void*)(&L[vbase * 4]),
                16, 0, 0);
        }
    }
    // Prefetch targets while DMA is in flight (coalesced dword loads).
    const int t0 = tsrc[tid];                                  // cell tid (tid < 324 always)
    const int t1 = (tid < CELLS - THREADS) ? tsrc[tid + THREADS] : 0;
    __syncthreads();   // drains DMA (compiler: s_waitcnt vmcnt(0) before s_barrier)

    // ---- Pass 1: cell-per-thread softmax; probs overwrite logits IN PLACE ----
    float acc_a = 0.0f;   // sum of (ce + 0.1*entropy) over owned cells
    #pragma unroll
    for (int it = 0; it < 2; ++it) {
        const int cell = tid + it * THREADS;
        if (cell < CELLS) {
            float* __restrict__ xp = &L[cell * 9];   // stride-9 words: 2-way alias = free
            const int t = (it == 0) ? t0 : t1;
            float x[9], e[9];
            #pragma unroll
            for (int i = 0; i < 9; ++i) x[i] = xp[i];
            // no max-subtract: logits ~N(0,1); fp32 exp cannot overflow (r5/r6: absmax 0.0)
            float s = 0.0f, sx = 0.0f;
            #pragma unroll
            for (int i = 0; i < 9; ++i) {
                e[i] = __expf(x[i]);
                s += e[i];
                sx = fmaf(e[i], x[i], sx);
            }
            float xt = x[0];
            #pragma unroll
            for (int i = 1; i < 9; ++i) xt = (i == t) ? x[i] : xt;
            const float lse = __logf(s);
            const float inv = __builtin_amdgcn_rcpf(s);
            acc_a += (lse - xt) + 0.1f * (lse - sx * inv);
            #pragma unroll
            for (int i = 0; i < 9; ++i) xp[i] = e[i] * inv;   // probs in place
        }
    }
    __syncthreads();

    // ---- Pass 2: one (board, unit) per thread; 27 units x 4 boards = 108 active ----
    float acc_c = 0.0f;
    if (tid < 27 * BPB) {
        const int q    = tid & 3;            // board (consecutive lanes: stride 729 = odd -> clean banks)
        const int u27  = tid >> 2;           // 0..26
        const int type = u27 / 9;            // 0=row 1=col 2=box
        const int unit = u27 - type * 9;
        const int ur3  = (unit / 3) * 3;
        const int uc3  = (unit % 3) * 3;
        const float* __restrict__ Pq = &L[q * 729];

        float acc[9];
        #pragma unroll
        for (int d = 0; d < 9; ++d) acc[d] = 0.0f;
        #pragma unroll
        for (int j = 0; j < 9; ++j) {
            const int crow = unit * 9 + j;
            const int ccol = j * 9 + unit;
            const int cbox = (ur3 + j / 3) * 9 + uc3 + (j % 3);
            const int c = (type == 0) ? crow : ((type == 1) ? ccol : cbox);
            const float* __restrict__ cp = Pq + c * 9;
            #pragma unroll
            for (int d = 0; d < 9; ++d) acc[d] += cp[d];   // ds_read2_b32-merged
        }
        #pragma unroll
        for (int d = 0; d < 9; ++d) {
            const float dd = acc[d] - 1.0f;
            acc_c = fmaf(dd, dd, acc_c);
        }
    }

    // ---- Block reduce: pre-scaled partial -> plain store (no global atomics) ----
    // loss = sum(ce + 0.1*ent)/(B*81) + [0.5/(27*B*9)] * sum((s-1)^2)
    const float SA = 1.0f / (65536.0f * 81.0f);
    const float SB = 0.5f / (27.0f * 65536.0f * 9.0f);
    float total = acc_a * SA + acc_c * SB;
    #pragma unroll
    for (int off = 32; off > 0; off >>= 1)
        total += __shfl_down(total, off, 64);
    if ((tid & 63) == 0) wave_sums[tid >> 6] = total;
    __syncthreads();
    if (tid == 0)
        partials[blockIdx.x] = wave_sums[0] + wave_sums[1] + wave_sums[2] + wave_sums[3];
}

__launch_bounds__(THREADS)
static __global__ void sudoku_final(const float* __restrict__ partials,
                                    float*       __restrict__ out) {
    __shared__ float wave_sums[THREADS / 64];
    const int tid = threadIdx.x;
    const float4* __restrict__ p4 = (const float4*)partials;
    float s = 0.0f;
    #pragma unroll 4
    for (int i = tid; i < NBLK / 4; i += THREADS) {   // coalesced float4
        const float4 v = p4[i];
        s += (v.x + v.y) + (v.z + v.w);
    }
    #pragma unroll
    for (int off = 32; off > 0; off >>= 1)
        s += __shfl_down(s, off, 64);
    if ((tid & 63) == 0) wave_sums[tid >> 6] = s;
    __syncthreads();
    if (tid == 0)
        out[0] = wave_sums[0] + wave_sums[1] + wave_sums[2] + wave_sums[3];
}

extern "C" void kernel_launch(void* const* d_in, const int* in_sizes, int n_in,
                              void* d_out, int out_size, void* d_ws, size_t ws_size,
                              hipStream_t stream) {
    const float* outs    = (const float*)d_in[0];
    const int*   targets = (const int*)d_in[1];
    float*       partials = (float*)d_ws;            // 16384 floats = 64 KB scratch
    hipLaunchKernelGGL(sudoku_main, dim3(NBLK), dim3(THREADS), 0, stream,
                       outs, targets, partials);
    hipLaunchKernelGGL(sudoku_final, dim3(1), dim3(THREADS), 0, stream,
                       partials, (float*)d_out);
}

// Round 8
// 281.305 us; speedup vs baseline: 1.0687x; 1.0687x over previous
//
#include <hip/hip_runtime.h>
#include <stdint.h>

#define THREADS 64                // ONE wave per block: no __syncthreads anywhere
#define SPB 4                     // boards per block (729 float4 logits exactly)
#define NBLK (65536 / SPB)        // 16384 blocks
#define NUNIT (27 * SPB)          // 108 (unit,board) tasks per block

static __global__ void sudoku_main(const float* __restrict__ outs,
                                   const int*   __restrict__ targets,
                                   float*       __restrict__ partials) {
    // Private per-wave slice: logits + targets. 11664 + 1296 B = 25.9 KB -> 6 blocks/CU.
    __shared__ __align__(16) float L[SPB * 729];
    __shared__ __align__(16) int   T[SPB * 81];

    const int lane = threadIdx.x;          // 0..63
    const long long board0 = (long long)blockIdx.x * SPB;
    const float* __restrict__ gsrc = outs + board0 * 729;
    const int*   __restrict__ tsrc = targets + board0 * 81;

    // ---- DMA: 729 float4 logits + 81 float4 targets into this wave's slice ----
    // (global_load_lds width 16: wave-uniform LDS base, HW lands lane l at base+16l)
    #pragma unroll
    for (int k = 0; k < 12; ++k) {
        const int idx = k * 64 + lane;
        if (idx < 729) {
            __builtin_amdgcn_global_load_lds(
                (const __attribute__((address_space(1))) void*)(gsrc + (size_t)idx * 4),
                (__attribute__((address_space(3))) void*)(&L[k * 256]),
                16, 0, 0);
        }
    }
    #pragma unroll
    for (int k = 0; k < 2; ++k) {
        const int idx = k * 64 + lane;
        if (idx < 81) {
            __builtin_amdgcn_global_load_lds(
                (const __attribute__((address_space(1))) void*)(tsrc + (size_t)idx * 4),
                (__attribute__((address_space(3))) void*)(&T[k * 256]),
                16, 0, 0);
        }
    }
    // Wave-private drain: only THIS wave stalls; sibling blocks keep computing.
    asm volatile("s_waitcnt vmcnt(0)" ::: "memory");

    // ---- 108 (unit,board) tasks over 2 wave-iterations; recompute softmax ----
    // (structure verified in r6: absmax 0.0. Rows partition cells once -> CE/entropy
    //  lives on row units; col/box units recompute exp at ~free trans-pipe cost.)
    float acc_a = 0.0f, acc_c = 0.0f;
    #pragma unroll
    for (int it = 0; it < 2; ++it) {
        const int u = it * 64 + lane;
        if (u < NUNIT) {
            const int b    = u & 3;              // board fastest: lane stride 729 words (mod 32 = 25)
            const int u27  = u >> 2;             // 0..26
            const int type = u27 / 9;            // 0=row 1=col 2=box
            const int unit = u27 - type * 9;
            const int ur3  = (unit / 3) * 3;
            const int uc3  = (unit % 3) * 3;
            const float* __restrict__ Lb = &L[b * 729];
            const int*   __restrict__ Tb = &T[b * 81];

            float acc[9];
            #pragma unroll
            for (int d = 0; d < 9; ++d) acc[d] = 0.0f;

            #pragma unroll
            for (int k = 0; k < 9; ++k) {
                const int cbox = (ur3 + k / 3) * 9 + uc3 + (k % 3);
                const int c = (type == 0) ? (unit * 9 + k)
                            : ((type == 1) ? (k * 9 + unit) : cbox);
                const float* __restrict__ xp = Lb + c * 9;
                float x[9], e[9];
                #pragma unroll
                for (int i = 0; i < 9; ++i) x[i] = xp[i];
                // no max-subtract: logits ~N(0,1); fp32 exp safe (r5-r7: absmax 0.0)
                float s = 0.0f, sx = 0.0f;
                #pragma unroll
                for (int i = 0; i < 9; ++i) {
                    e[i] = __expf(x[i]);
                    s += e[i];
                    sx = fmaf(e[i], x[i], sx);
                }
                const float inv = __builtin_amdgcn_rcpf(s);
                #pragma unroll
                for (int i = 0; i < 9; ++i) acc[i] = fmaf(e[i], inv, acc[i]);

                if (type == 0) {                 // CE + 0.1*entropy, row units only
                    const float xt  = xp[Tb[c]]; // one LDS read beats cndmask chain
                    const float lse = __logf(s);
                    acc_a += (lse - xt) + 0.1f * (lse - sx * inv);
                }
            }
            #pragma unroll
            for (int d = 0; d < 9; ++d) {
                const float dd = acc[d] - 1.0f;
                acc_c = fmaf(dd, dd, acc_c);
            }
        }
    }

    // ---- Wave reduce (no LDS, no barrier), plain store of block partial ----
    // loss = sum(ce + 0.1*ent)/(B*81) + [0.5/(27*B*9)] * sum((s-1)^2)
    const float SA = 1.0f / (65536.0f * 81.0f);
    const float SB = 0.5f / (27.0f * 65536.0f * 9.0f);
    float total = acc_a * SA + acc_c * SB;
    #pragma unroll
    for (int off = 32; off > 0; off >>= 1)
        total += __shfl_down(total, off, 64);
    if (lane == 0)
        partials[blockIdx.x] = total;
}

__launch_bounds__(256)
static __global__ void sudoku_final(const float* __restrict__ partials,
                                    float*       __restrict__ out) {
    __shared__ float wave_sums[4];
    const int tid = threadIdx.x;
    const float4* __restrict__ p4 = (const float4*)partials;
    float s = 0.0f;
    #pragma unroll 4
    for (int i = tid; i < NBLK / 4; i += 256) {   // coalesced float4
        const float4 v = p4[i];
        s += (v.x + v.y) + (v.z + v.w);
    }
    #pragma unroll
    for (int off = 32; off > 0; off >>= 1)
        s += __shfl_down(s, off, 64);
    if ((tid & 63) == 0) wave_sums[tid >> 6] = s;
    __syncthreads();
    if (tid == 0)
        out[0] = wave_sums[0] + wave_sums[1] + wave_sums[2] + wave_sums[3];
}

extern "C" void kernel_launch(void* const* d_in, const int* in_sizes, int n_in,
                              void* d_out, int out_size, void* d_ws, size_t ws_size,
                              hipStream_t stream) {
    const float* outs    = (const float*)d_in[0];
    const int*   targets = (const int*)d_in[1];
    float*       partials = (float*)d_ws;            // 16384 floats = 64 KB scratch
    hipLaunchKernelGGL(sudoku_main, dim3(NBLK), dim3(THREADS), 0, stream,
                       outs, targets, partials);
    hipLaunchKernelGGL(sudoku_final, dim3(1), dim3(256), 0, stream,
                       partials, (float*)d_out);
}